// Round 8
// baseline (219.134 us; speedup 1.0000x reference)
//
#include <hip/hip_runtime.h>
#include <hip/hip_bf16.h>

// DenseAttention — reassociated (6.44 GF vs 155 GF direct), bf16 MFMA.
// Round 8: fuse all 5 round-7 dispatches into ONE kernel with a manual
// monotonic-counter grid barrier (round-5 coop-launch API failed; this avoids
// it). Grid = 256 blocks = #CUs; residency guaranteed (LDS 48.6KB -> 3
// blocks/CU, VGPR ~116 -> >=2, so all 256 fit under any packing).
//   P0: prep  xb=bf16(x), xt=bf16(x^T), qb=bf16(qw), cb=bf16(comb^T), zero G+Wt
//   P1: gram  G[bq][f][h] += xt_f . xt_h      256 jobs, split-K8, atomic
//   P2: 2a    Tt[ba][g][qf] = cb_g . G_f      128 jobs
//   P3: 2b    Wt[ba][g][e] += Tt_g . qb_e     128 jobs, split-K4, atomic
//   P4: out   out[t][ag]   = xb_t . Wt_g      256 jobs
// All phase bodies verbatim from round 7 (PASS, absmax 1.953e-3); barriers
// give inter-phase ordering + cross-XCD visibility (threadfence release /
// acquire around device-scope atomic counter, zeroed by a 64B memsetAsync).
// ws: G 2MB@0 | Wt 2MB@2 | Tt 8MB@4 | xb 8MB@12 | xt 8MB@20 | qb 2MB@28 |
//     cb 2MB@30 | bar @32MB.

typedef unsigned short u16;
using short8  = __attribute__((ext_vector_type(8))) short;
using floatx4 = __attribute__((ext_vector_type(4))) float;

__device__ inline u16 f2bf(float f) {               // RNE f32->bf16
    unsigned u = __float_as_uint(f);
    unsigned r = u + 0x7fffu + ((u >> 16) & 1u);
    return (u16)(r >> 16);
}

// Row-major source [128 m][64 k] (k-contiguous) -> fragment-major LDS.
template <typename T>
__device__ inline void stage_row(const T* __restrict__ src, long ld,
                                 u16* __restrict__ dst, int tid) {
#pragma unroll
    for (int it = 0; it < 8; ++it) {
        const int flat = (it * 256 + tid) * 4;
        const int kl = flat & 63, rl = flat >> 6;
        ushort4 v;
        if (sizeof(T) == 4) {
            const float4 f = *(const float4*)&((const float*)src)[(long)rl * ld + kl];
            v.x = f2bf(f.x); v.y = f2bf(f.y); v.z = f2bf(f.z); v.w = f2bf(f.w);
        } else {
            v = *(const ushort4*)&((const u16*)src)[(long)rl * ld + kl];
        }
        const int chunk = ((kl >> 5) * 8 + (rl >> 4)) * 64 + ((kl >> 3) & 3) * 16 + (rl & 15);
        *(ushort4*)&dst[chunk * 8 + (kl & 7)] = v;
    }
}

// C[m0+..128, n0+..128] (+)= A . B^T (A:[128 m][K], B:[128 n][K], k-contiguous).
template <typename TA, typename TB, bool ATOMIC>
__device__ inline void gemm_tile(const TA* __restrict__ A, long lda,
                                 const TB* __restrict__ B, long ldb,
                                 float* __restrict__ C, long ldc,
                                 int K, int m0, int n0,
                                 u16* __restrict__ As, u16* __restrict__ Bs) {
    const int tid = threadIdx.x, lane = tid & 63, w = tid >> 6;
    const int IA = (w & 1) * 4, JB = (w >> 1) * 4;
    floatx4 acc[4][4] = {};

    for (int k0 = 0; k0 < K; k0 += 64) {
        stage_row(A + k0, lda, As, tid);
        stage_row(B + k0, ldb, Bs, tid);
        __syncthreads();
#pragma unroll
        for (int s = 0; s < 2; ++s) {
            short8 af[4], bfr[4];
#pragma unroll
            for (int i = 0; i < 4; ++i)
                af[i] = *(const short8*)&As[((s * 8 + IA + i) * 64 + lane) * 8];
#pragma unroll
            for (int j = 0; j < 4; ++j)
                bfr[j] = *(const short8*)&Bs[((s * 8 + JB + j) * 64 + lane) * 8];
#pragma unroll
            for (int i = 0; i < 4; ++i)
#pragma unroll
                for (int j = 0; j < 4; ++j)
                    acc[i][j] = __builtin_amdgcn_mfma_f32_16x16x32_bf16(af[i], bfr[j], acc[i][j], 0, 0, 0);
        }
        __syncthreads();
    }
    const int rb = (lane >> 4) * 4, col = lane & 15;
#pragma unroll
    for (int i = 0; i < 4; ++i)
#pragma unroll
        for (int j = 0; j < 4; ++j)
#pragma unroll
            for (int r = 0; r < 4; ++r) {
                const int gm = m0 + IA * 16 + i * 16 + rb + r;
                const int gn = n0 + JB * 16 + j * 16 + col;
                float* p = &C[(long)gm * ldc + gn];
                if (ATOMIC) atomicAdd(p, acc[i][j][r]); else *p = acc[i][j][r];
            }
}

// 64x64 f32 tile transpose src[r0+..][c0+..] -> bf16 dst[c0+..][r0+..]
__device__ inline void transpose64(const float* __restrict__ src, long lds_,
                                   int r0, int c0,
                                   u16* __restrict__ dst, long ldd,
                                   float (*tile)[65], int t) {
#pragma unroll
    for (int it = 0; it < 4; ++it) {
        const int row = (t >> 4) + it * 16, cq = (t & 15) * 4;
        *(float4*)&tile[row][cq] = *(const float4*)&src[(long)(r0 + row) * lds_ + c0 + cq];
    }
    __syncthreads();
#pragma unroll
    for (int it = 0; it < 4; ++it) {
        const int cl = (t >> 4) + it * 16, rq = (t & 15) * 4;
        ushort4 v;
        v.x = f2bf(tile[rq + 0][cl]); v.y = f2bf(tile[rq + 1][cl]);
        v.z = f2bf(tile[rq + 2][cl]); v.w = f2bf(tile[rq + 3][cl]);
        *(ushort4*)&dst[(long)(c0 + cl) * ldd + r0 + rq] = v;
    }
}

// Monotonic-counter grid barrier: bar zeroed before launch; each of 256 blocks
// arrives once per call; works for any number of barriers. Device-scope atomics
// + threadfence give cross-XCD ordering/visibility.
__device__ inline void grid_barrier(unsigned* __restrict__ bar) {
    __syncthreads();
    if (threadIdx.x == 0) {
        __threadfence();                                 // release prior writes
        const unsigned old = atomicAdd(bar, 1u);         // device scope
        const unsigned target = (old / 256u + 1u) * 256u;
        while (__hip_atomic_load(bar, __ATOMIC_RELAXED,
                                 __HIP_MEMORY_SCOPE_AGENT) < target)
            __builtin_amdgcn_s_sleep(2);
        __threadfence();                                 // acquire
    }
    __syncthreads();
}

__global__ __launch_bounds__(256) void k_fused(const float* __restrict__ x,
                                               const float* __restrict__ qw,
                                               const float* __restrict__ comb,
                                               float* __restrict__ out,
                                               float* __restrict__ G,
                                               float* __restrict__ Tt,
                                               float* __restrict__ Wt,
                                               u16* __restrict__ xb,
                                               u16* __restrict__ xt,
                                               u16* __restrict__ qb,
                                               u16* __restrict__ cb,
                                               unsigned* __restrict__ bar) {
    __shared__ u16 As[8192];
    __shared__ u16 Bs[8192];
    __shared__ float tile[64][65];
    const int bid = blockIdx.x, t = threadIdx.x;

    // ---- P0: prep (1600 jobs over 256 blocks) ----
    for (int j = bid; j < 1600; j += 256) {
        if (j < 1024) {               // x: xb (bf16 copy) + xt (bf16 transpose)
            const int b = j >> 9, local = j & 511;
            const int u0 = (local & 31) * 64, f0 = (local >> 5) * 64;
            const float* src = x + (long)b * 2097152;
#pragma unroll
            for (int it = 0; it < 4; ++it) {
                const int row = (t >> 4) + it * 16, cq = (t & 15) * 4;
                const float4 f = *(const float4*)&src[(long)(u0 + row) * 1024 + f0 + cq];
                *(float4*)&tile[row][cq] = f;
                ushort4 v;
                v.x = f2bf(f.x); v.y = f2bf(f.y); v.z = f2bf(f.z); v.w = f2bf(f.w);
                *(ushort4*)&xb[(long)b * 2097152 + (long)(u0 + row) * 1024 + f0 + cq] = v;
            }
            __syncthreads();
#pragma unroll
            for (int it = 0; it < 4; ++it) {
                const int cl = (t >> 4) + it * 16, rq = (t & 15) * 4;
                ushort4 v;
                v.x = f2bf(tile[rq + 0][cl]); v.y = f2bf(tile[rq + 1][cl]);
                v.z = f2bf(tile[rq + 2][cl]); v.w = f2bf(tile[rq + 3][cl]);
                *(ushort4*)&xt[(long)b * 2097152 + (long)(f0 + cl) * 2048 + u0 + rq] = v;
            }
        } else if (j < 1280) {        // qw -> qb straight convert
            const long base = (long)(j - 1024) * 4096;
#pragma unroll
            for (int it = 0; it < 4; ++it) {
                const long off = base + (it * 256 + t) * 4;
                const float4 f = *(const float4*)&qw[off];
                ushort4 v;
                v.x = f2bf(f.x); v.y = f2bf(f.y); v.z = f2bf(f.z); v.w = f2bf(f.w);
                *(ushort4*)&qb[off] = v;
            }
        } else if (j < 1536) {        // comb[a][k][g] -> cb[a][g][k]
            const int idx = j - 1280, a = idx >> 6, local = idx & 63;
            const int k0 = (local & 15) * 64, g0 = (local >> 4) * 64;
            transpose64(comb + (long)a * 262144, 256, k0, g0,
                        cb + (long)a * 262144, 1024, tile, t);
        } else {                      // zero G + Wt (4 MB contiguous at G)
            float4 zero = {0.f, 0.f, 0.f, 0.f};
            float4* z = (float4*)G;
#pragma unroll
            for (int it = 0; it < 16; ++it)
                z[(long)(j - 1536) * 4096 + it * 256 + t] = zero;
        }
        __syncthreads();              // tile reuse across j iterations
    }
    grid_barrier(bar);

    // ---- P1: gram. G[bq][f][h] += xt_f . xt_h  (256 jobs) ----
    {
        const int tl = bid & 3, bq = (bid >> 2) & 7, split = bid >> 5;
        const int tm = tl >> 1, tn = tl & 1;
        const int b = bq >> 2, q = bq & 3;
        const u16* base = xt + (long)b * 2097152 + (long)q * 256 * 2048 + split * 256;
        gemm_tile<u16, u16, true>(base + (long)tm * 128 * 2048, 2048,
                                  base + (long)tn * 128 * 2048, 2048,
                                  G + (long)bq * 65536, 256,
                                  256, tm * 128, tn * 128, As, Bs);
    }
    grid_barrier(bar);

    // ---- P2: 2a. Tt[ba][g][q*256+f] = cb_g . G_f  (128 jobs) ----
    if (bid < 128) {
        const int tl = bid & 3, i = bid >> 2;        // i = ba*4+q
        const int tm = tl >> 1, tn = tl & 1;
        const int q = i & 3, ba = i >> 2, b = ba >> 2, a = ba & 3;
        gemm_tile<u16, float, false>(
            cb + (long)a * 262144 + (long)tm * 128 * 1024 + q * 256, 1024,
            G + (long)(b * 4 + q) * 65536 + (long)tn * 128 * 256, 256,
            Tt + (long)ba * 262144, 1024,
            256, tm * 128, q * 256 + tn * 128, As, Bs);
    }
    grid_barrier(bar);

    // ---- P3: 2b. Wt[ba][g][e] += Tt_g . qb_e  (128 jobs, split-K4) ----
    if (bid < 128) {
        const int tl = bid & 3, ba = (bid >> 2) & 7, split = bid >> 5;
        const int tm = tl >> 1, tn = tl & 1;
        const int a = ba & 3;
        gemm_tile<float, u16, true>(
            Tt + (long)ba * 262144 + (long)tm * 128 * 1024 + split * 256, 1024,
            qb + (long)a * 262144 + (long)tn * 128 * 1024 + split * 256, 1024,
            Wt + (long)ba * 65536, 256,
            256, tm * 128, tn * 128, As, Bs);
    }
    grid_barrier(bar);

    // ---- P4: out[b][t][a*256+g] = xb_t . Wt_g  (256 jobs) ----
    {
        const int tl = bid & 31, ba = bid >> 5;
        const int tm = tl >> 1, tn = tl & 1;
        const int b = ba >> 2, a = ba & 3;
        gemm_tile<u16, float, false>(
            xb + (long)b * 2097152 + (long)tm * 128 * 1024 + a * 256, 1024,
            Wt + (long)ba * 65536 + (long)tn * 128 * 256, 256,
            out + (long)b * 2097152 + a * 256, 1024,
            256, tm * 128, tn * 128, As, Bs);
    }
}

extern "C" void kernel_launch(void* const* d_in, const int* in_sizes, int n_in,
                              void* d_out, int out_size, void* d_ws, size_t ws_size,
                              hipStream_t stream) {
    const float* x    = (const float*)d_in[0];   // [2,2048,1024]
    const float* qw   = (const float*)d_in[1];   // [4,256,1024]
    const float* comb = (const float*)d_in[2];   // [4,1024,256]
    float* out = (float*)d_out;

    char* ws = (char*)d_ws;
    float* G  = (float*)(ws);                    // 2 MB [8][256x256]  (G,Wt contiguous: zeroed in P0)
    float* Wt = (float*)(ws + (2u << 20));       // 2 MB [8][256][256]  Wt[g][e]
    float* Tt = (float*)(ws + (4u << 20));       // 8 MB [8][256][1024] Tt[g][qf]
    u16* xb   = (u16*)  (ws + (12u << 20));      // 8 MB [2][2048][1024]
    u16* xt   = (u16*)  (ws + (20u << 20));      // 8 MB [2][1024][2048]
    u16* qb   = (u16*)  (ws + (28u << 20));      // 2 MB [4][256][1024]
    u16* cb   = (u16*)  (ws + (30u << 20));      // 2 MB [4][256][1024]
    unsigned* bar = (unsigned*)(ws + (32u << 20));

    hipMemsetAsync(bar, 0, 64, stream);          // barrier counter init
    k_fused<<<256, 256, 0, stream>>>(x, qw, comb, out, G, Tt, Wt,
                                     xb, xt, qb, cb, bar);
}

// Round 9
// 143.866 us; speedup vs baseline: 1.5232x; 1.5232x over previous
//
#include <hip/hip_runtime.h>
#include <hip/hip_bf16.h>

// DenseAttention — reassociated (6.44 GF vs 155 GF direct), bf16 MFMA.
// Round 9: revert round-8 fusion (spin-barrier fusion cost +60% — cross-XCD
// fence L2 flushes + slowest-block serialization). Keep round-7's 5 stream-
// ordered dispatches, but fix the latency-bound phases (busy% <12 at ~1
// block/CU) with 4x oversubscription: 64x64 block tiles (wave = 32x32 = 2x2
// mfma_16x16x32_bf16), 16 KB LDS/block -> 2-4 blocks/CU per phase.
//   prep:  xt=bf16(x^T), cb[a][g][k]=bf16(comb[a][k][g]), zero G+Wt   1536 blk
//   gram:  G[bq][f][h] += xt_f . xt_h     grid(16,8,8)=1024, split-K8, atomic
//   2a:    Tt[ba][g][qf] = cb_g . G_f     grid(16,32) =512
//   2b:    Wt[ba][g][e] += Tt_g . qw_e    grid(16,8,4)=512, split-K4, atomic
//   out:   out[t][ag]   = x_t . Wt_g      grid(128,8) =1024
// xb/qb buffers deleted: f32 sources (x, qw, G, Tt, Wt) are converted in the
// stager (bitwise-identical values to round 7's precomputed bf16 copies).
// All stores coalesced; atomics coalesced. Fragment-major LDS (conflict-free
// ds_read_b128), layouts = round-7-verified modulo MT=4 tiling.
// ws (22 MB): G 2 | Wt 2 | Tt 8 | xt 8 | cb 2.

typedef unsigned short u16;
using short8  = __attribute__((ext_vector_type(8))) short;
using floatx4 = __attribute__((ext_vector_type(4))) float;

__device__ inline u16 f2bf(float f) {               // RNE f32->bf16
    unsigned u = __float_as_uint(f);
    unsigned r = u + 0x7fffu + ((u >> 16) & 1u);
    return (u16)(r >> 16);
}

// Row-major source [64 m][64 k] (k-contiguous) -> fragment-major LDS (MT=4).
// Element (m,k): lane=((k&31)>>3)*16+(m&15), j=k&7,
// chunk=((k>>5)*4+(m>>4))*64+lane; As = 8 chunk-groups x 64 lanes x 8 u16 = 8KB.
template <typename T>
__device__ inline void stage64(const T* __restrict__ src, long ld,
                               u16* __restrict__ dst, int tid) {
#pragma unroll
    for (int it = 0; it < 4; ++it) {
        const int flat = (it * 256 + tid) * 4;
        const int kl = flat & 63, rl = flat >> 6;
        ushort4 v;
        if (sizeof(T) == 4) {
            const float4 f = *(const float4*)&((const float*)src)[(long)rl * ld + kl];
            v.x = f2bf(f.x); v.y = f2bf(f.y); v.z = f2bf(f.z); v.w = f2bf(f.w);
        } else {
            v = *(const ushort4*)&((const u16*)src)[(long)rl * ld + kl];
        }
        const int chunk = ((kl >> 5) * 4 + (rl >> 4)) * 64 + ((kl >> 3) & 3) * 16 + (rl & 15);
        *(ushort4*)&dst[chunk * 8 + (kl & 7)] = v;
    }
}

// C[m0+..64, n0+..64] (+)= A . B^T  (A:[64 m][K], B:[64 n][K], k-contiguous).
// 4 waves: wave w computes 32x32 at (IA=(w&1)*2, JB=(w>>1)*2) in 16-tiles.
template <typename TA, typename TB, bool ATOMIC>
__device__ inline void gemm_tile(const TA* __restrict__ A, long lda,
                                 const TB* __restrict__ B, long ldb,
                                 float* __restrict__ C, long ldc,
                                 int K, int m0, int n0) {
    __shared__ u16 As[4096];   // 8 KB
    __shared__ u16 Bs[4096];
    const int tid = threadIdx.x, lane = tid & 63, w = tid >> 6;
    const int IA = (w & 1) * 2, JB = (w >> 1) * 2;
    floatx4 acc[2][2] = {};

    for (int k0 = 0; k0 < K; k0 += 64) {
        stage64(A + k0, lda, As, tid);
        stage64(B + k0, ldb, Bs, tid);
        __syncthreads();
#pragma unroll
        for (int s = 0; s < 2; ++s) {
            short8 af[2], bfr[2];
#pragma unroll
            for (int i = 0; i < 2; ++i)
                af[i] = *(const short8*)&As[((s * 4 + IA + i) * 64 + lane) * 8];
#pragma unroll
            for (int j = 0; j < 2; ++j)
                bfr[j] = *(const short8*)&Bs[((s * 4 + JB + j) * 64 + lane) * 8];
#pragma unroll
            for (int i = 0; i < 2; ++i)
#pragma unroll
                for (int j = 0; j < 2; ++j)
                    acc[i][j] = __builtin_amdgcn_mfma_f32_16x16x32_bf16(af[i], bfr[j], acc[i][j], 0, 0, 0);
        }
        __syncthreads();
    }
    const int rb = (lane >> 4) * 4, col = lane & 15;
#pragma unroll
    for (int i = 0; i < 2; ++i)
#pragma unroll
        for (int j = 0; j < 2; ++j)
#pragma unroll
            for (int r = 0; r < 4; ++r) {
                const int gm = m0 + (IA + i) * 16 + rb + r;
                const int gn = n0 + (JB + j) * 16 + col;
                float* p = &C[(long)gm * ldc + gn];
                if (ATOMIC) atomicAdd(p, acc[i][j][r]); else *p = acc[i][j][r];
            }
}

// 64x64 f32 tile transpose src[r0+..][c0+..] -> bf16 dst[c0+..][r0+..]
__device__ inline void transpose64(const float* __restrict__ src, long lds_,
                                   int r0, int c0,
                                   u16* __restrict__ dst, long ldd,
                                   float (*tile)[65], int t) {
#pragma unroll
    for (int it = 0; it < 4; ++it) {
        const int row = (t >> 4) + it * 16, cq = (t & 15) * 4;
        *(float4*)&tile[row][cq] = *(const float4*)&src[(long)(r0 + row) * lds_ + c0 + cq];
    }
    __syncthreads();
#pragma unroll
    for (int it = 0; it < 4; ++it) {
        const int cl = (t >> 4) + it * 16, rq = (t & 15) * 4;
        ushort4 v;
        v.x = f2bf(tile[rq + 0][cl]); v.y = f2bf(tile[rq + 1][cl]);
        v.z = f2bf(tile[rq + 2][cl]); v.w = f2bf(tile[rq + 3][cl]);
        *(ushort4*)&dst[(long)(c0 + cl) * ldd + r0 + rq] = v;
    }
}

__global__ __launch_bounds__(256) void k_prep(const float* __restrict__ x,
                                              const float* __restrict__ comb,
                                              u16* __restrict__ xt,
                                              u16* __restrict__ cb,
                                              float* __restrict__ GZ) {
    __shared__ float tile[64][65];
    const int j = blockIdx.x, t = threadIdx.x;
    if (j < 1024) {                   // xt[b][f][u] = bf16(x[b][u][f])
        const int b = j >> 9, local = j & 511;
        const int u0 = (local & 31) * 64, f0 = (local >> 5) * 64;
        transpose64(x + (long)b * 2097152, 1024, u0, f0,
                    xt + (long)b * 2097152, 2048, tile, t);
    } else if (j < 1280) {            // cb[a][g][k] = bf16(comb[a][k][g])
        const int idx = j - 1024, a = idx >> 6, local = idx & 63;
        const int k0 = (local & 15) * 64, g0 = (local >> 4) * 64;
        transpose64(comb + (long)a * 262144, 256, k0, g0,
                    cb + (long)a * 262144, 1024, tile, t);
    } else {                          // zero G + Wt (4 MB contiguous at GZ)
        const int idx = j - 1280;     // 256 jobs x 16 KB
        float4 zero = {0.f, 0.f, 0.f, 0.f};
        float4* z = (float4*)GZ;
#pragma unroll
        for (int it = 0; it < 4; ++it)
            z[(long)idx * 1024 + it * 256 + t] = zero;
    }
}

// gram: G[bq][f][h] += sum_{u in split} xt[b][qf][u] * xt[b][qh][u]
__global__ __launch_bounds__(256) void k_gram(const u16* __restrict__ xt,
                                              float* __restrict__ G) {
    const int tile = blockIdx.x, bq = blockIdx.y, split = blockIdx.z;
    const int tm = tile >> 2, tn = tile & 3;
    const int b = bq >> 2, q = bq & 3;
    const u16* base = xt + (long)b * 2097152 + (long)q * 256 * 2048 + split * 256;
    gemm_tile<u16, u16, true>(base + (long)tm * 64 * 2048, 2048,
                              base + (long)tn * 64 * 2048, 2048,
                              G + (long)bq * 65536, 256,
                              256, tm * 64, tn * 64);
}

// 2a: Tt[ba][g][q*256+f] = sum_h cb[a][g][q*256+h] * G[bq][f][h]
__global__ __launch_bounds__(256) void k_2a(const u16* __restrict__ cb,
                                            const float* __restrict__ G,
                                            float* __restrict__ Tt) {
    const int tile = blockIdx.x, i = blockIdx.y;     // i = ba*4+q
    const int tm = tile >> 2, tn = tile & 3;
    const int q = i & 3, ba = i >> 2, b = ba >> 2, a = ba & 3;
    gemm_tile<u16, float, false>(
        cb + (long)a * 262144 + (long)tm * 64 * 1024 + q * 256, 1024,
        G + (long)(b * 4 + q) * 65536 + (long)tn * 64 * 256, 256,
        Tt + (long)ba * 262144, 1024,
        256, tm * 64, q * 256 + tn * 64);
}

// 2b: Wt[ba][g][e] += sum_{k in split} Tt[ba][g][k] * qw[a][e][k]
__global__ __launch_bounds__(256) void k_2b(const float* __restrict__ Tt,
                                            const float* __restrict__ qw,
                                            float* __restrict__ Wt) {
    const int tile = blockIdx.x, ba = blockIdx.y, split = blockIdx.z;
    const int tm = tile >> 2, tn = tile & 3;
    const int a = ba & 3;
    gemm_tile<float, float, true>(
        Tt + (long)ba * 262144 + (long)tm * 64 * 1024 + split * 256, 1024,
        qw + (long)a * 262144 + (long)tn * 64 * 1024 + split * 256, 1024,
        Wt + (long)ba * 65536, 256,
        256, tm * 64, tn * 64);
}

// out: out[b][t][a*256+g] = sum_e x[b][t][a*256+e] * Wt[ba][g][e]
__global__ __launch_bounds__(256) void k_3(const float* __restrict__ x,
                                           const float* __restrict__ Wt,
                                           float* __restrict__ out) {
    const int tl = blockIdx.x, ba = blockIdx.y;      // tl: tm 0..31, tn 0..3
    const int tm = tl >> 2, tn = tl & 3;
    const int b = ba >> 2, a = ba & 3;
    gemm_tile<float, float, false>(
        x + (long)b * 2097152 + (long)tm * 64 * 1024 + a * 256, 1024,
        Wt + (long)ba * 65536 + (long)tn * 64 * 256, 256,
        out + (long)b * 2097152 + a * 256, 1024,
        256, tm * 64, tn * 64);
}

extern "C" void kernel_launch(void* const* d_in, const int* in_sizes, int n_in,
                              void* d_out, int out_size, void* d_ws, size_t ws_size,
                              hipStream_t stream) {
    const float* x    = (const float*)d_in[0];   // [2,2048,1024]
    const float* qw   = (const float*)d_in[1];   // [4,256,1024]
    const float* comb = (const float*)d_in[2];   // [4,1024,256]
    float* out = (float*)d_out;

    char* ws = (char*)d_ws;
    float* G  = (float*)(ws);                    // 2 MB [8][256x256] (G,Wt contiguous: zeroed in prep)
    float* Wt = (float*)(ws + (2u << 20));       // 2 MB [8][256][256]  Wt[g][e]
    float* Tt = (float*)(ws + (4u << 20));       // 8 MB [8][256][1024] Tt[g][qf]
    u16* xt   = (u16*)  (ws + (12u << 20));      // 8 MB [2][1024][2048]
    u16* cb   = (u16*)  (ws + (20u << 20));      // 2 MB [4][256][1024]

    k_prep<<<1536, 256, 0, stream>>>(x, comb, xt, cb, G);
    k_gram<<<dim3(16, 8, 8), 256, 0, stream>>>(xt, G);
    k_2a  <<<dim3(16, 32),   256, 0, stream>>>(cb, G, Tt);
    k_2b  <<<dim3(16, 8, 4), 256, 0, stream>>>(Tt, qw, Wt);
    k_3   <<<dim3(128, 8),   256, 0, stream>>>(x, Wt, out);
}